// Round 3
// baseline (424.961 us; speedup 1.0000x reference)
//
#include <hip/hip_runtime.h>
#include <stdint.h>

// Problem constants (setup_inputs: T=4096, B=4096, C=2)
#define T_STEPS 4096
#define B_SIZE  4096
#define NWORDS  (T_STEPS / 32)         // 128 packed words of 32 timesteps each
#define TB      ((size_t)T_STEPS * B_SIZE)

// BETA_MEM = 0.9, BETA_INH = 0.6, THRESHOLD = 1.0
// Reference step (per batch element b):
//   cur_exc = x0*w00 + x1*w01
//   inh     = 0.6*inh + x0
//   cur_inh = w_inh * inh
//   cur     = cur_exc + cur_inh
//   reset   = (mem > 1)           // spike_fn(mem - 1): equivalent for f32
//   mem     = (0.9*mem + cur) - reset
//   spk     = (mem > 1)
// Outputs: spk_rec, exc_rec(=cur_exc), inh_rec(=cur_inh), mem_rec, each (T,B).
//
// Scratch layout is parameterized by `cks` (elements between consecutive word
// indices i):
//   - workspace path:  cks = B       (dense 4 MiB arrays in d_ws)
//   - in-output path:  cks = 32*B    (slot (i,b) lives at out-region[i*32*B+b],
//     i.e. the t=32i row of each output record; K2 thread (i,bq) reads only its
//     own 4 slots per record before its k=0 stores overwrite them -> no race)

// ---------------------------------------------------------------------------
// K0: pack spike bits. x is (T,B,2) f32 with values exactly 0.0 or 1.0.
// Each thread packs TWO batch elements via float4 loads (16 B/lane).
// ---------------------------------------------------------------------------
__global__ __launch_bounds__(256) void k_pack(const float4* __restrict__ x,
                                              uint32_t* __restrict__ p0,
                                              uint32_t* __restrict__ p1,
                                              uint32_t cks) {
    uint32_t gid = blockIdx.x * 256u + threadIdx.x;   // NWORDS * B/2 threads
    uint32_t i  = gid >> 11;                          // word index (B/2 == 2048)
    uint32_t bh = gid & (B_SIZE / 2 - 1);             // batch-pair index
    const float4* xp = x + (size_t)i * 32u * (B_SIZE / 2) + bh;
    uint32_t a0 = 0u, a1 = 0u, b0 = 0u, b1 = 0u;
#pragma unroll
    for (int k = 0; k < 32; ++k) {
        float4 v = xp[(size_t)k * (B_SIZE / 2)];
        a0 |= (uint32_t)(v.x != 0.0f) << k;   // b = 2*bh,   channel 0
        a1 |= (uint32_t)(v.y != 0.0f) << k;   // b = 2*bh,   channel 1
        b0 |= (uint32_t)(v.z != 0.0f) << k;   // b = 2*bh+1, channel 0
        b1 |= (uint32_t)(v.w != 0.0f) << k;   // b = 2*bh+1, channel 1
    }
    size_t o = (size_t)i * cks + 2u * bh;     // even -> 8B-aligned uint2 store
    *(uint2*)&p0[o] = make_uint2(a0, b0);
    *(uint2*)&p1[o] = make_uint2(a1, b1);
}

// ---------------------------------------------------------------------------
// K1: serial scan over T per batch element, from packed bits.
// Writes exact state checkpoints (mem, inh) BEFORE each 32-step word.
// Regions p0/p1 vs mem_ck/inh_ck are disjoint in BOTH layouts -> restrict ok.
// ---------------------------------------------------------------------------
__global__ __launch_bounds__(256) void k_scan(const uint32_t* __restrict__ p0,
                                              const uint32_t* __restrict__ p1,
                                              const float* __restrict__ w_exc,
                                              const float* __restrict__ w_inh_p,
                                              float* __restrict__ mem_ck,
                                              float* __restrict__ inh_ck,
                                              uint32_t cks) {
    int b = blockIdx.x * 256 + threadIdx.x;
    const float w00 = w_exc[0], w01 = w_exc[1], winh = w_inh_p[0];
    float mem = 0.0f, inh = 0.0f;

    if (w00 == 0.0f && winh == 0.0f) {
        // Fast path: cur = w01*x1 exactly; inh does not affect mem.
        uint32_t w1 = p1[b];
        for (int i = 0; i < NWORDS; ++i) {
            uint32_t w1n = (i + 1 < NWORDS) ? p1[(size_t)(i + 1) * cks + b] : 0u;
            mem_ck[(size_t)i * cks + b] = mem;
#pragma unroll
            for (int k = 0; k < 32; ++k) {
                float x1f = (float)((w1 >> k) & 1u);
                float r   = (mem > 1.0f) ? 1.0f : 0.0f;  // old-mem reset (parallel to mul)
                float m1  = __fmul_rn(0.9f, mem);
                // x1f*w01 is exact (x in {0,1}), so this fma == round(m1 + cur).
                float m2  = __fmaf_rn(x1f, w01, m1);
                mem       = __fsub_rn(m2, r);
            }
            w1 = w1n;
        }
    } else {
        uint32_t w0 = p0[b], w1 = p1[b];
        for (int i = 0; i < NWORDS; ++i) {
            uint32_t w0n = (i + 1 < NWORDS) ? p0[(size_t)(i + 1) * cks + b] : 0u;
            uint32_t w1n = (i + 1 < NWORDS) ? p1[(size_t)(i + 1) * cks + b] : 0u;
            mem_ck[(size_t)i * cks + b] = mem;
            inh_ck[(size_t)i * cks + b] = inh;
#pragma unroll
            for (int k = 0; k < 32; ++k) {
                float x0f = (float)((w0 >> k) & 1u);
                float x1f = (float)((w1 >> k) & 1u);
                float exc = __fadd_rn(__fmul_rn(x0f, w00), __fmul_rn(x1f, w01));
                inh       = __fadd_rn(__fmul_rn(0.6f, inh), x0f);
                float ci  = __fmul_rn(winh, inh);
                float cur = __fadd_rn(exc, ci);
                float r   = (mem > 1.0f) ? 1.0f : 0.0f;
                float m1  = __fmul_rn(0.9f, mem);
                float m2  = __fadd_rn(m1, cur);
                mem       = __fsub_rn(m2, r);
            }
            w0 = w0n; w1 = w1n;
        }
    }
}

// ---------------------------------------------------------------------------
// Per-step helpers — bit-identical rounding to the reference step.
// ---------------------------------------------------------------------------
__device__ __forceinline__ void step_fast(float& mem, uint32_t w1, int k, float w01,
                                          float& exc, float& spk) {
    float x1f = (float)((w1 >> k) & 1u);
    exc       = __fmul_rn(x1f, w01);              // == cur_exc exactly
    float r   = (mem > 1.0f) ? 1.0f : 0.0f;
    float m1  = __fmul_rn(0.9f, mem);
    float m2  = __fmaf_rn(x1f, w01, m1);          // identical rounding to add
    mem       = __fsub_rn(m2, r);
    spk       = (mem > 1.0f) ? 1.0f : 0.0f;
}

__device__ __forceinline__ void step_gen(float& mem, float& inh,
                                         uint32_t w0, uint32_t w1, int k,
                                         float w00, float w01, float winh,
                                         float& exc, float& ci, float& spk) {
    float x0f = (float)((w0 >> k) & 1u);
    float x1f = (float)((w1 >> k) & 1u);
    exc       = __fadd_rn(__fmul_rn(x0f, w00), __fmul_rn(x1f, w01));
    inh       = __fadd_rn(__fmul_rn(0.6f, inh), x0f);
    ci        = __fmul_rn(winh, inh);
    float cur = __fadd_rn(exc, ci);
    float r   = (mem > 1.0f) ? 1.0f : 0.0f;
    float m1  = __fmul_rn(0.9f, mem);
    float m2  = __fadd_rn(m1, cur);
    mem       = __fsub_rn(m2, r);
    spk       = (mem > 1.0f) ? 1.0f : 0.0f;
}

// ---------------------------------------------------------------------------
// K2: parallel replay. One thread per (32-step chunk, batch QUAD); starts from
// the exact checkpoints and writes all 4 output records via float4 stores
// (16 B/lane — the measured HBM sweet spot; K2 writes all 256 MiB of output).
// NO __restrict__ on aliasable pointers: in the in-output layout the scratch
// aliases `out` (each thread's slots are its own k=0 store addresses; reads
// are issued first in program order and must stay there without restrict).
// ---------------------------------------------------------------------------
__global__ __launch_bounds__(256) void k_replay(const uint32_t* p0,
                                                const uint32_t* p1,
                                                const float* __restrict__ w_exc,
                                                const float* __restrict__ w_inh_p,
                                                const float* mem_ck,
                                                const float* inh_ck,
                                                float* out,
                                                uint32_t cks) {
    uint32_t gid = blockIdx.x * 256u + threadIdx.x;   // NWORDS * B/4 threads
    uint32_t i  = gid >> 10;                          // word index (B/4 == 1024)
    uint32_t bq = gid & (B_SIZE / 4 - 1);             // batch-quad index
    uint32_t b  = bq * 4u;
    float* spk_o = out;
    float* exc_o = out + TB;
    float* inh_o = out + 2 * TB;
    float* mem_o = out + 3 * TB;
    const float w00 = w_exc[0], w01 = w_exc[1], winh = w_inh_p[0];
    size_t slot = (size_t)i * cks + b;                // 16B-aligned (b%4==0, cks%4==0)
    float4 mem  = *(const float4*)&mem_ck[slot];
    size_t base = (size_t)i * 32u * B_SIZE + b;

    if (w00 == 0.0f && winh == 0.0f) {
        uint4 w1 = *(const uint4*)&p1[slot];
        const float4 zero = make_float4(0.0f, 0.0f, 0.0f, 0.0f);
#pragma unroll
        for (int k = 0; k < 32; ++k) {
            float4 e, s;
            step_fast(mem.x, w1.x, k, w01, e.x, s.x);
            step_fast(mem.y, w1.y, k, w01, e.y, s.y);
            step_fast(mem.z, w1.z, k, w01, e.z, s.z);
            step_fast(mem.w, w1.w, k, w01, e.w, s.w);
            size_t idx = base + (size_t)k * B_SIZE;
            *(float4*)&spk_o[idx] = s;
            *(float4*)&exc_o[idx] = e;
            *(float4*)&inh_o[idx] = zero;             // w_inh * inh == +0
            *(float4*)&mem_o[idx] = mem;
        }
    } else {
        float4 inh = *(const float4*)&inh_ck[slot];
        uint4 w0 = *(const uint4*)&p0[slot];
        uint4 w1 = *(const uint4*)&p1[slot];
#pragma unroll
        for (int k = 0; k < 32; ++k) {
            float4 e, c, s;
            step_gen(mem.x, inh.x, w0.x, w1.x, k, w00, w01, winh, e.x, c.x, s.x);
            step_gen(mem.y, inh.y, w0.y, w1.y, k, w00, w01, winh, e.y, c.y, s.y);
            step_gen(mem.z, inh.z, w0.z, w1.z, k, w00, w01, winh, e.z, c.z, s.z);
            step_gen(mem.w, inh.w, w0.w, w1.w, k, w00, w01, winh, e.w, c.w, s.w);
            size_t idx = base + (size_t)k * B_SIZE;
            *(float4*)&spk_o[idx] = s;
            *(float4*)&exc_o[idx] = e;
            *(float4*)&inh_o[idx] = c;
            *(float4*)&mem_o[idx] = mem;
        }
    }
}

extern "C" void kernel_launch(void* const* d_in, const int* in_sizes, int n_in,
                              void* d_out, int out_size, void* d_ws, size_t ws_size,
                              hipStream_t stream) {
    const float4* x4    = (const float4*)d_in[0];   // (T,B,2) f32, read as pairs
    const float*  w_exc = (const float*)d_in[1];    // (1,2) f32
    const float*  w_inh = (const float*)d_in[2];    // scalar f32
    float* out = (float*)d_out;

    const size_t nw = (size_t)NWORDS * B_SIZE;
    const size_t need = nw * (sizeof(uint32_t) * 2 + sizeof(float) * 2); // 8 MiB

    uint32_t *p0, *p1;
    float *mem_ck, *inh_ck;
    uint32_t cks;
    if (ws_size >= need) {
        // Dense scratch in the provided workspace.
        p0     = (uint32_t*)d_ws;
        p1     = p0 + nw;
        mem_ck = (float*)(p1 + nw);
        inh_ck = mem_ck + nw;
        cks    = B_SIZE;
    } else {
        // Workspace-free: stash slot (i,b) at the t=32*i row of each output
        // record. K2 thread (i,bq) reads exactly its own slots before its
        // own k=0 stores overwrite them; no other thread touches them.
        p0     = (uint32_t*)out;              // spk region
        p1     = (uint32_t*)(out + TB);       // exc region
        inh_ck = out + 2 * TB;                // inh region
        mem_ck = out + 3 * TB;                // mem region
        cks    = 32u * B_SIZE;
    }

    // K0: pack (T/32 * B/2 threads, 2 batch elements each via float4)
    k_pack<<<(NWORDS * (B_SIZE / 2)) / 256, 256, 0, stream>>>(x4, p0, p1, cks);
    // K1: serial checkpoint scan (B threads)
    k_scan<<<B_SIZE / 256, 256, 0, stream>>>(p0, p1, w_exc, w_inh, mem_ck, inh_ck, cks);
    // K2: parallel replay + output (T/32 * B/4 threads, float4 stores)
    k_replay<<<(NWORDS * (B_SIZE / 4)) / 256, 256, 0, stream>>>(p0, p1, w_exc, w_inh,
                                                                mem_ck, inh_ck, out, cks);
}